// Round 9
// baseline (218.120 us; speedup 1.0000x reference)
//
#include <hip/hip_runtime.h>
#include <hip/hip_bf16.h>

#define NEG 0.2f
#define NBC 1568       // bucket array size (>= 1563 real buckets of 64 nodes)
#define BCAP 3328      // per-bucket capacity: mean 2048 + 28 sigma
#define TILE 12500     // edges per kP block (3.2M / 256 exactly)
#define EPT 25         // max edges per thread in kP (ceil(12500/512))

// ---------- kP: 256 balanced blocks; 64-node buckets; LDS counting sort ----------
// packed word = (src << 6) | (dst & 63)
__global__ void __launch_bounds__(512) kP_bucket(
    const int* __restrict__ src, const int* __restrict__ dst,
    int* __restrict__ gcur, unsigned int* __restrict__ packed, int E, int NB)
{
    __shared__ int hist[NBC], lofs[NBC], gbase[NBC], cur[NBC];
    __shared__ int wtot[8], wpre[8];
    __shared__ unsigned int stage[TILE];
    int tid = threadIdx.x;
    int lane = tid & 63, wv = tid >> 6;
    for (int j = tid; j < NBC; j += 512) hist[j] = 0;
    __syncthreads();
    int t0 = blockIdx.x * TILE;
    int tend = t0 + TILE; if (tend > E) tend = E;
    int dreg[EPT];
    #pragma unroll
    for (int k = 0; k < EPT; ++k) {
        int i = t0 + tid + (k << 9);
        int d = -1;
        if (i < tend) { d = dst[i]; atomicAdd(&hist[d >> 6], 1); }
        dreg[k] = d;
    }
    __syncthreads();
    // exclusive scan of NBC counts: 4 elems/thread, wave shfl-scan, 2 barriers
    int e0 = 0, e1 = 0, e2 = 0, e3 = 0, idx0 = 4 * tid;
    if (idx0 < NBC) { e0 = hist[idx0]; e1 = hist[idx0+1]; e2 = hist[idx0+2]; e3 = hist[idx0+3]; }
    int ssum = e0 + e1 + e2 + e3;
    int incl = ssum;
    #pragma unroll
    for (int off = 1; off < 64; off <<= 1) {
        int t = __shfl_up(incl, off, 64);
        if (lane >= off) incl += t;
    }
    if (lane == 63) wtot[wv] = incl;
    __syncthreads();
    if (tid == 0) { int p = 0; for (int i = 0; i < 8; ++i) { wpre[i] = p; p += wtot[i]; } }
    __syncthreads();
    if (idx0 < NBC) {
        int base = wpre[wv] + incl - ssum;
        lofs[idx0] = base;         base += e0;
        lofs[idx0+1] = base;       base += e1;
        lofs[idx0+2] = base;       base += e2;
        lofs[idx0+3] = base;
    }
    for (int j = tid; j < NBC; j += 512) {
        int h = hist[j];
        gbase[j] = h ? atomicAdd(&gcur[j], h) : 0;   // one global atomic per (block,bucket)
        cur[j] = 0;
    }
    __syncthreads();
    // stage edges ordered by bucket (src re-read coalesced; dst from regs)
    #pragma unroll
    for (int k = 0; k < EPT; ++k) {
        int d = dreg[k];
        if (d >= 0) {
            int i = t0 + tid + (k << 9);
            int j = d >> 6;
            int pos = lofs[j] + atomicAdd(&cur[j], 1);
            stage[pos] = ((unsigned)src[i] << 6) | (unsigned)(d & 63);
        }
    }
    __syncthreads();
    // write contiguous runs: 4 subgroups of 16 lanes per wave
    int sg = lane >> 4, sl = lane & 15;
    for (int j = wv * 4 + sg; j < NB; j += 32) {
        int h = hist[j];
        if (!h) continue;
        int lo = lofs[j], gb = gbase[j];
        for (int k = sl; k < h; k += 16) {
            int gp = gb + k;
            if (gp < BCAP) packed[(size_t)j * BCAP + gp] = stage[lo + k];
        }
    }
}

// ---------- kL1: per-64-node-bucket sort + register gather + fused k3 + in-place csr ----------
__global__ void __launch_bounds__(256) kL1(
    const int* __restrict__ gcur, unsigned int* packed,
    const float* __restrict__ x,
    const float* __restrict__ W1, const float* __restrict__ as1, const float* __restrict__ ad1,
    const float* __restrict__ b1, const float* __restrict__ W2,
    const float* __restrict__ as2w, const float* __restrict__ ad2w,
    int* __restrict__ rowS, int* __restrict__ rowE,
    float* __restrict__ h2, float* __restrict__ as2, float* __restrict__ ad2, int N)
{
    __shared__ int hist[64], roff[64], cur[64];
    __shared__ int stage[BCAP];
    __shared__ float S1[8], D1[8], sW1[64], sb1[64], sW2[512], sas[8], sad[8];
    int tid = threadIdx.x, b = blockIdx.x;
    if (tid < 8) {
        float sv = 0.f, dv = 0.f;
        for (int c = 0; c < 8; ++c) {
            float w = W1[tid * 8 + c];
            sv += w * as1[tid * 8 + c];
            dv += w * ad1[tid * 8 + c];
        }
        S1[tid] = sv; D1[tid] = dv;
        sas[tid] = as2w[tid]; sad[tid] = ad2w[tid];
    }
    if (tid < 64) { sW1[tid] = W1[tid]; sb1[tid] = b1[tid]; hist[tid] = 0; }
    sW2[tid] = W2[tid]; sW2[tid + 256] = W2[tid + 256];
    __syncthreads();
    int cnt = gcur[b]; if (cnt > BCAP) cnt = BCAP;
    size_t base = (size_t)b * BCAP;
    unsigned int* pk = packed + base;
    for (int i = tid; i < cnt; i += 256)
        atomicAdd(&hist[pk[i] & 63], 1);
    __syncthreads();
    if (tid < 64) {                      // single-wave inclusive scan of 64 bins
        int v = hist[tid];
        int s = v;
        #pragma unroll
        for (int off = 1; off < 64; off <<= 1) {
            int t = __shfl_up(s, off, 64);
            if (tid >= off) s += t;
        }
        roff[tid] = s;
        cur[tid] = s - v;                // exclusive start
    }
    __syncthreads();
    for (int i = tid; i < cnt; i += 256) {
        unsigned p = pk[i];
        int pos = atomicAdd(&cur[p & 63], 1);
        stage[pos] = (int)(p >> 6);      // src index
    }
    __syncthreads();
    // in-place csr writeback (block owns region) + row bounds
    for (int i = tid; i < cnt; i += 256)
        pk[i] = (unsigned)stage[i];
    int nl = tid >> 2, sub = tid & 3;    // 4 lanes per node
    int node = b * 64 + nl;
    bool valid = node < N;
    int en = roff[nl], st = en - hist[nl];
    if (valid && sub == 0) { rowS[node] = (int)base + st; rowE[node] = (int)base + en; }
    float xdv = valid ? x[node] : 0.f;
    float s1r[8], d1r[8];
    #pragma unroll
    for (int h = 0; h < 8; ++h) { s1r[h] = S1[h]; d1r[h] = D1[h]; }
    float num[8] = {0,0,0,0,0,0,0,0}, den[8] = {0,0,0,0,0,0,0,0};
    if (valid && sub == 0) {             // self loop
        #pragma unroll
        for (int h = 0; h < 8; ++h) {
            float e = xdv * (s1r[h] + d1r[h]);
            e = fmaxf(e, NEG * e);
            float w = __expf(e);
            den[h] = w; num[h] = w * xdv;
        }
    }
    for (int j = st + sub; j < en; j += 4) {
        float xsv = x[stage[j]];
        #pragma unroll
        for (int h = 0; h < 8; ++h) {
            float e = xsv * s1r[h] + xdv * d1r[h];
            e = fmaxf(e, NEG * e);
            float w = __expf(e);
            den[h] += w; num[h] += w * xsv;
        }
    }
    #pragma unroll
    for (int h = 0; h < 8; ++h) {
        den[h] += __shfl_xor(den[h], 1, 64);
        num[h] += __shfl_xor(num[h], 1, 64);
        den[h] += __shfl_xor(den[h], 2, 64);
        num[h] += __shfl_xor(num[h], 2, 64);
    }
    if (!valid || sub) return;
    // fused k3: normalize, +b1, elu, @W2, attention scalars
    float o[8] = {0,0,0,0,0,0,0,0};
    #pragma unroll
    for (int h = 0; h < 8; ++h) {
        float agg = num[h] / (den[h] + 1e-16f);
        #pragma unroll
        for (int c = 0; c < 8; ++c) {
            float vv = agg * sW1[h * 8 + c] + sb1[h * 8 + c];
            vv = vv > 0.f ? vv : (__expf(vv) - 1.f);   // elu
            #pragma unroll
            for (int c2 = 0; c2 < 8; ++c2) o[c2] += vv * sW2[(h * 8 + c) * 8 + c2];
        }
    }
    float as_ = 0.f, ad_ = 0.f;
    #pragma unroll
    for (int c = 0; c < 8; ++c) {
        as_ += o[c] * sas[c];
        ad_ += o[c] * sad[c];
        h2[(size_t)node * 8 + c] = o[c];
    }
    as2[node] = as_; ad2[node] = ad_;
}

// ---------- kG2: layer-2 gather, 8 lanes per dst node (validated) ----------
__global__ void __launch_bounds__(256) kG2_gather(
    const int* __restrict__ rowS, const int* __restrict__ rowE,
    const unsigned int* __restrict__ csr,
    const float* __restrict__ as2, const float* __restrict__ ad2,
    const float* __restrict__ h2,
    float* __restrict__ out2, int N)
{
    int t = blockIdx.x * blockDim.x + threadIdx.x;
    int node = t >> 3, lane = t & 7;
    if (node >= N) return;
    float add = ad2[node];
    float den = 0.f, num[8] = {0,0,0,0,0,0,0,0};
    if (lane == 0) {            // self loop
        float e = as2[node] + add;
        e = fmaxf(e, NEG * e);
        float w = __expf(e);
        den = w;
        const float4* hp = (const float4*)&h2[(size_t)node * 8];
        float4 a = hp[0], b = hp[1];
        num[0] = w * a.x; num[1] = w * a.y; num[2] = w * a.z; num[3] = w * a.w;
        num[4] = w * b.x; num[5] = w * b.y; num[6] = w * b.z; num[7] = w * b.w;
    }
    int start = rowS[node], end = rowE[node];
    for (int j = start + lane; j < end; j += 8) {
        int s = (int)csr[j];
        float e = as2[s] + add;
        e = fmaxf(e, NEG * e);
        float w = __expf(e);
        den += w;
        const float4* hp = (const float4*)&h2[(size_t)s * 8];
        float4 a = hp[0], b = hp[1];
        num[0] += w * a.x; num[1] += w * a.y; num[2] += w * a.z; num[3] += w * a.w;
        num[4] += w * b.x; num[5] += w * b.y; num[6] += w * b.z; num[7] += w * b.w;
    }
    #pragma unroll
    for (int off = 4; off >= 1; off >>= 1) {
        den += __shfl_down(den, off, 8);
        #pragma unroll
        for (int c = 0; c < 8; ++c) num[c] += __shfl_down(num[c], off, 8);
    }
    if (lane == 0) {
        float dv = den + 1e-16f;
        #pragma unroll
        for (int c = 0; c < 8; ++c) out2[(size_t)node * 8 + c] = num[c] / dv;
    }
}

// ---------- kB: graph start offsets from sorted batch ----------
__global__ void __launch_bounds__(256) kB_starts(
    const int* __restrict__ batch, int* __restrict__ gstart, int N, int G)
{
    int n = blockIdx.x * blockDim.x + threadIdx.x;
    if (n >= N) return;
    int b0 = batch[n];
    if (n == 0) {
        for (int g = 0; g <= b0; ++g) gstart[g] = 0;
    } else {
        int bp = batch[n - 1];
        for (int g = bp + 1; g <= b0; ++g) gstart[g] = n;
    }
    if (n == N - 1) {
        for (int g = b0 + 1; g <= G; ++g) gstart[g] = N;
    }
}

// ---------- kPool: one wave per graph — mean pool + b2 + linear + log_softmax ----------
__global__ void __launch_bounds__(256) kPool(
    const float* __restrict__ out2, const int* __restrict__ gstart,
    const float* __restrict__ b2v,
    const float* __restrict__ lin_w, const float* __restrict__ lin_b,
    float* __restrict__ out, int G)
{
    __shared__ float sw[80], sb[10], sb2[8];
    if (threadIdx.x < 80) sw[threadIdx.x] = lin_w[threadIdx.x];
    if (threadIdx.x < 10) sb[threadIdx.x] = lin_b[threadIdx.x];
    if (threadIdx.x < 8)  sb2[threadIdx.x] = b2v[threadIdx.x];
    __syncthreads();
    int wid = (blockIdx.x * blockDim.x + threadIdx.x) >> 6;
    if (wid >= G) return;
    int lane = threadIdx.x & 63;
    int ch = lane & 7, sub = lane >> 3;
    int start = gstart[wid], end = gstart[wid + 1];
    int cntn = end - start;
    float acc = 0.f;
    for (int i = start + sub; i < end; i += 8)
        acc += out2[(size_t)i * 8 + ch];       // fully coalesced
    acc += __shfl_down(acc, 32, 64);
    acc += __shfl_down(acc, 16, 64);
    acc += __shfl_down(acc, 8, 64);
    float inv = (cntn > 0) ? 1.f / (float)cntn : 0.f;
    float p[8];
    #pragma unroll
    for (int i = 0; i < 8; ++i) {
        float tt = __shfl(acc, i, 64);
        p[i] = (cntn > 0) ? (tt * inv + sb2[i]) : 0.f;
    }
    float l[10]; float m = -1e30f;
    #pragma unroll
    for (int j = 0; j < 10; ++j) {
        float v = sb[j];
        #pragma unroll
        for (int i = 0; i < 8; ++i) v += p[i] * sw[i * 10 + j];
        l[j] = v; m = v > m ? v : m;
    }
    float sum = 0.f;
    #pragma unroll
    for (int j = 0; j < 10; ++j) sum += __expf(l[j] - m);
    float lse = m + __logf(sum);
    if (lane < 10) out[(size_t)wid * 10 + lane] = l[lane] - lse;
}

extern "C" void kernel_launch(void* const* d_in, const int* in_sizes, int n_in,
                              void* d_out, int out_size, void* d_ws, size_t ws_size,
                              hipStream_t stream) {
    const float* x    = (const float*)d_in[0];
    const int*   ei   = (const int*)d_in[1];
    const int*   batch= (const int*)d_in[2];
    const float* W1   = (const float*)d_in[4];
    const float* as1  = (const float*)d_in[5];
    const float* ad1  = (const float*)d_in[6];
    const float* b1   = (const float*)d_in[7];
    const float* W2   = (const float*)d_in[8];
    const float* as2w = (const float*)d_in[9];
    const float* ad2w = (const float*)d_in[10];
    const float* b2v  = (const float*)d_in[11];
    const float* lw   = (const float*)d_in[12];
    const float* lb   = (const float*)d_in[13];
    float* out = (float*)d_out;

    const int N = in_sizes[0];            // 100000
    const int E = in_sizes[1] / 2;        // 3200000
    const int G = out_size / 10;          // 512
    const int* srcI = ei;
    const int* dstI = ei + E;
    const int NB = (N + 63) >> 6;         // 1563 buckets of 64 nodes

    // workspace layout
    int*   gcur = (int*)d_ws;                                // NBC (pad 2048)
    unsigned int* packed = (unsigned int*)(gcur + 2048);     // NBC*BCAP (~21 MB; csr in-place)
    int*   rowS = (int*)(packed + (size_t)NBC * BCAP);       // N
    int*   rowE = rowS + N;                                  // N
    float* h2   = (float*)(rowE + N);                        // 8N
    float* as2  = h2 + (size_t)8 * N;                        // N
    float* ad2  = as2 + N;                                   // N
    float* out2 = ad2 + N;                                   // 8N
    int*   gstart = (int*)(out2 + (size_t)8 * N);            // G+1

    const int B = 256;
    hipMemsetAsync(gcur, 0, 2048 * sizeof(int), stream);

    kP_bucket<<<(E + TILE - 1) / TILE, 512, 0, stream>>>(srcI, dstI, gcur, packed, E, NB);
    kB_starts<<<(N + B - 1) / B, B, 0, stream>>>(batch, gstart, N, G);
    kL1<<<NB, B, 0, stream>>>(gcur, packed, x, W1, as1, ad1, b1, W2, as2w, ad2w,
                              rowS, rowE, h2, as2, ad2, N);
    kG2_gather<<<(N * 8 + B - 1) / B, B, 0, stream>>>(rowS, rowE, packed, as2, ad2, h2,
                                                      out2, N);
    kPool<<<(G * 64 + B - 1) / B, B, 0, stream>>>(out2, gstart, b2v, lw, lb, out, G);
}

// Round 11
// 199.175 us; speedup vs baseline: 1.0951x; 1.0951x over previous
//
#include <hip/hip_runtime.h>
#include <hip/hip_bf16.h>

#define NEG 0.2f
#define NBMAX 512      // bucket table size (391 real buckets of 256 nodes)
#define BCAP 12288     // per-bucket capacity: mean 8184 + 45 sigma
#define TILE 12500     // edges per kP block (3.2M / 256 exactly)
#define EPT 13         // edges per thread in kP (ceil(12500/1024))

// ---------- kP: 256 balanced blocks x 1024 threads; 256-node buckets; LDS counting sort ----------
// packed word = (src << 8) | (dst & 255)
__global__ void __launch_bounds__(1024) kP_bucket(
    const int* __restrict__ src, const int* __restrict__ dst,
    int* __restrict__ gcur, unsigned int* __restrict__ packed, int E, int NB)
{
    __shared__ int hist[NBMAX], lofs[NBMAX], gbase[NBMAX], cur[NBMAX];
    __shared__ int wtot[8], wpre[8];
    __shared__ unsigned int stage[TILE];
    int tid = threadIdx.x;
    int lane = tid & 63, wv = tid >> 6;           // 16 waves
    if (tid < NBMAX) hist[tid] = 0;
    __syncthreads();
    int t0 = blockIdx.x * TILE;
    int tend = t0 + TILE; if (tend > E) tend = E;
    int dreg[EPT];
    #pragma unroll
    for (int k = 0; k < EPT; ++k) {
        int i = t0 + tid + (k << 10);
        int d = -1;
        if (i < tend) { d = dst[i]; atomicAdd(&hist[d >> 8], 1); }
        dreg[k] = d;
    }
    __syncthreads();
    // exclusive scan of 512 counts: first 8 waves, 1 elem/lane, shfl wave-scan
    int v = (tid < NBMAX) ? hist[tid] : 0;
    int incl = v;
    #pragma unroll
    for (int off = 1; off < 64; off <<= 1) {
        int t = __shfl_up(incl, off, 64);
        if (lane >= off) incl += t;
    }
    if (tid < NBMAX && lane == 63) wtot[wv] = incl;
    __syncthreads();
    if (tid == 0) { int p = 0; for (int i = 0; i < 8; ++i) { wpre[i] = p; p += wtot[i]; } }
    __syncthreads();
    if (tid < NBMAX) {
        lofs[tid] = wpre[wv] + incl - v;
        gbase[tid] = v ? atomicAdd(&gcur[tid], v) : 0;   // one global atomic per (block,bucket)
        cur[tid] = 0;
    }
    __syncthreads();
    // stage edges ordered by bucket (src re-read coalesced; dst from regs)
    #pragma unroll
    for (int k = 0; k < EPT; ++k) {
        int d = dreg[k];
        if (d >= 0) {
            int i = t0 + tid + (k << 10);
            int j = d >> 8;
            int pos = lofs[j] + atomicAdd(&cur[j], 1);
            stage[pos] = ((unsigned)src[i] << 8) | (unsigned)(d & 255);
        }
    }
    __syncthreads();
    // write contiguous runs (~32 dwords): 2 subgroups of 32 lanes per wave
    int sg = lane >> 5, sl = lane & 31;
    for (int j = wv * 2 + sg; j < NB; j += 32) {
        int h = hist[j];
        if (!h) continue;
        int lo = lofs[j], gb = gbase[j];
        for (int k = sl; k < h; k += 32) {
            int gp = gb + k;
            if (gp < BCAP) packed[(size_t)j * BCAP + gp] = stage[lo + k];
        }
    }
}

// ---------- kL1: per-bucket LDS sort (once) + register gather + fused k3 + csr writeback
//             + folded kB (graph start offsets) ----------
__global__ void __launch_bounds__(512) kL1(
    const int* __restrict__ gcur, unsigned int* packed,
    const float* __restrict__ x,
    const float* __restrict__ W1, const float* __restrict__ as1, const float* __restrict__ ad1,
    const float* __restrict__ b1, const float* __restrict__ W2,
    const float* __restrict__ as2w, const float* __restrict__ ad2w,
    const int* __restrict__ batch, int* __restrict__ gstart,
    int* __restrict__ rowS, int* __restrict__ rowE,
    float* __restrict__ h2, float* __restrict__ as2, float* __restrict__ ad2, int N, int G)
{
    __shared__ int hist[256], roff[256], cur[256];
    __shared__ int stage[BCAP];
    __shared__ float S1[8], D1[8], sW1[64], sb1[64], sW2[512], sas[8], sad[8];
    int tid = threadIdx.x, b = blockIdx.x;
    if (tid < 8) {
        float sv = 0.f, dv = 0.f;
        for (int c = 0; c < 8; ++c) {
            float w = W1[tid * 8 + c];
            sv += w * as1[tid * 8 + c];
            dv += w * ad1[tid * 8 + c];
        }
        S1[tid] = sv; D1[tid] = dv;
        sas[tid] = as2w[tid]; sad[tid] = ad2w[tid];
    }
    for (int i = tid; i < 64; i += 512) { sW1[i] = W1[i]; sb1[i] = b1[i]; }
    if (tid < 512) sW2[tid] = W2[tid];
    if (tid < 256) hist[tid] = 0;
    // folded kB: graph start offsets from sorted batch (this block's 256 nodes)
    if (tid < 256) {
        int node = b * 256 + tid;
        if (node < N) {
            int b0 = batch[node];
            if (node == 0) { for (int g = 0; g <= b0; ++g) gstart[g] = 0; }
            else { int bp = batch[node - 1]; for (int g = bp + 1; g <= b0; ++g) gstart[g] = node; }
            if (node == N - 1) { for (int g = b0 + 1; g <= G; ++g) gstart[g] = N; }
        }
    }
    __syncthreads();
    int cnt = gcur[b]; if (cnt > BCAP) cnt = BCAP;
    size_t base = (size_t)b * BCAP;
    unsigned int* pk = packed + base;
    for (int i = tid; i < cnt; i += 512)
        atomicAdd(&hist[pk[i] & 255], 1);
    __syncthreads();
    int v = (tid < 256) ? hist[tid] : 0;
    if (tid < 256) roff[tid] = v;
    __syncthreads();
    for (int off = 1; off < 256; off <<= 1) {
        int t = (tid >= off && tid < 256) ? roff[tid - off] : 0;
        __syncthreads();
        if (tid < 256) roff[tid] += t;
        __syncthreads();
    }
    if (tid < 256) cur[tid] = roff[tid] - v;     // exclusive start
    __syncthreads();
    for (int i = tid; i < cnt; i += 512) {
        unsigned p = pk[i];
        int pos = atomicAdd(&cur[p & 255], 1);
        stage[pos] = (int)(p >> 8);              // src index
    }
    __syncthreads();
    // csr writeback (sorted src) + row bounds — kG2 reuses, no second sort
    for (int i = tid; i < cnt; i += 512)
        pk[i] = (unsigned)stage[i];
    int nl = tid >> 1, sub = tid & 1;            // 2 lanes per node
    int node = b * 256 + nl;
    bool valid = node < N;
    int en = roff[nl], st = en - hist[nl];
    if (valid && sub == 0) { rowS[node] = (int)base + st; rowE[node] = (int)base + en; }
    float xdv = valid ? x[node] : 0.f;
    float s1r[8], d1r[8];
    #pragma unroll
    for (int h = 0; h < 8; ++h) { s1r[h] = S1[h]; d1r[h] = D1[h]; }
    float num[8] = {0,0,0,0,0,0,0,0}, den[8] = {0,0,0,0,0,0,0,0};
    if (valid && sub == 0) {                     // self loop
        #pragma unroll
        for (int h = 0; h < 8; ++h) {
            float e = xdv * (s1r[h] + d1r[h]);
            e = fmaxf(e, NEG * e);
            float w = __expf(e);
            den[h] = w; num[h] = w * xdv;
        }
    }
    for (int j = st + sub; j < en; j += 2) {
        float xsv = x[stage[j]];
        #pragma unroll
        for (int h = 0; h < 8; ++h) {
            float e = xsv * s1r[h] + xdv * d1r[h];
            e = fmaxf(e, NEG * e);
            float w = __expf(e);
            den[h] += w; num[h] += w * xsv;
        }
    }
    #pragma unroll
    for (int h = 0; h < 8; ++h) {
        den[h] += __shfl_xor(den[h], 1, 64);
        num[h] += __shfl_xor(num[h], 1, 64);
    }
    if (!valid || sub) return;
    // fused k3: normalize, +b1, elu, @W2, attention scalars
    float o[8] = {0,0,0,0,0,0,0,0};
    #pragma unroll
    for (int h = 0; h < 8; ++h) {
        float agg = num[h] / (den[h] + 1e-16f);
        #pragma unroll
        for (int c = 0; c < 8; ++c) {
            float vv = agg * sW1[h * 8 + c] + sb1[h * 8 + c];
            vv = vv > 0.f ? vv : (__expf(vv) - 1.f);   // elu
            #pragma unroll
            for (int c2 = 0; c2 < 8; ++c2) o[c2] += vv * sW2[(h * 8 + c) * 8 + c2];
        }
    }
    float as_ = 0.f, ad_ = 0.f;
    #pragma unroll
    for (int c = 0; c < 8; ++c) {
        as_ += o[c] * sas[c];
        ad_ += o[c] * sad[c];
        h2[(size_t)node * 8 + c] = o[c];
    }
    as2[node] = as_; ad2[node] = ad_;
}

// ---------- kG2: layer-2 gather, 8 lanes per dst node (validated) ----------
__global__ void __launch_bounds__(256) kG2_gather(
    const int* __restrict__ rowS, const int* __restrict__ rowE,
    const unsigned int* __restrict__ csr,
    const float* __restrict__ as2, const float* __restrict__ ad2,
    const float* __restrict__ h2,
    float* __restrict__ out2, int N)
{
    int t = blockIdx.x * blockDim.x + threadIdx.x;
    int node = t >> 3, lane = t & 7;
    if (node >= N) return;
    float add = ad2[node];
    float den = 0.f, num[8] = {0,0,0,0,0,0,0,0};
    if (lane == 0) {            // self loop
        float e = as2[node] + add;
        e = fmaxf(e, NEG * e);
        float w = __expf(e);
        den = w;
        const float4* hp = (const float4*)&h2[(size_t)node * 8];
        float4 a = hp[0], b = hp[1];
        num[0] = w * a.x; num[1] = w * a.y; num[2] = w * a.z; num[3] = w * a.w;
        num[4] = w * b.x; num[5] = w * b.y; num[6] = w * b.z; num[7] = w * b.w;
    }
    int start = rowS[node], end = rowE[node];
    for (int j = start + lane; j < end; j += 8) {
        int s = (int)csr[j];
        float e = as2[s] + add;
        e = fmaxf(e, NEG * e);
        float w = __expf(e);
        den += w;
        const float4* hp = (const float4*)&h2[(size_t)s * 8];
        float4 a = hp[0], b = hp[1];
        num[0] += w * a.x; num[1] += w * a.y; num[2] += w * a.z; num[3] += w * a.w;
        num[4] += w * b.x; num[5] += w * b.y; num[6] += w * b.z; num[7] += w * b.w;
    }
    #pragma unroll
    for (int off = 4; off >= 1; off >>= 1) {
        den += __shfl_down(den, off, 8);
        #pragma unroll
        for (int c = 0; c < 8; ++c) num[c] += __shfl_down(num[c], off, 8);
    }
    if (lane == 0) {
        float dv = den + 1e-16f;
        #pragma unroll
        for (int c = 0; c < 8; ++c) out2[(size_t)node * 8 + c] = num[c] / dv;
    }
}

// ---------- kPool: one wave per graph — mean pool + b2 + linear + log_softmax ----------
__global__ void __launch_bounds__(256) kPool(
    const float* __restrict__ out2, const int* __restrict__ gstart,
    const float* __restrict__ b2v,
    const float* __restrict__ lin_w, const float* __restrict__ lin_b,
    float* __restrict__ out, int G)
{
    __shared__ float sw[80], sb[10], sb2[8];
    if (threadIdx.x < 80) sw[threadIdx.x] = lin_w[threadIdx.x];
    if (threadIdx.x < 10) sb[threadIdx.x] = lin_b[threadIdx.x];
    if (threadIdx.x < 8)  sb2[threadIdx.x] = b2v[threadIdx.x];
    __syncthreads();
    int wid = (blockIdx.x * blockDim.x + threadIdx.x) >> 6;
    if (wid >= G) return;
    int lane = threadIdx.x & 63;
    int ch = lane & 7, sub = lane >> 3;
    int start = gstart[wid], end = gstart[wid + 1];
    int cntn = end - start;
    float acc = 0.f;
    for (int i = start + sub; i < end; i += 8)
        acc += out2[(size_t)i * 8 + ch];       // fully coalesced
    acc += __shfl_down(acc, 32, 64);
    acc += __shfl_down(acc, 16, 64);
    acc += __shfl_down(acc, 8, 64);
    float inv = (cntn > 0) ? 1.f / (float)cntn : 0.f;
    float p[8];
    #pragma unroll
    for (int i = 0; i < 8; ++i) {
        float tt = __shfl(acc, i, 64);
        p[i] = (cntn > 0) ? (tt * inv + sb2[i]) : 0.f;
    }
    float l[10]; float m = -1e30f;
    #pragma unroll
    for (int j = 0; j < 10; ++j) {
        float v = sb[j];
        #pragma unroll
        for (int i = 0; i < 8; ++i) v += p[i] * sw[i * 10 + j];
        l[j] = v; m = v > m ? v : m;
    }
    float sum = 0.f;
    #pragma unroll
    for (int j = 0; j < 10; ++j) sum += __expf(l[j] - m);
    float lse = m + __logf(sum);
    if (lane < 10) out[(size_t)wid * 10 + lane] = l[lane] - lse;
}

extern "C" void kernel_launch(void* const* d_in, const int* in_sizes, int n_in,
                              void* d_out, int out_size, void* d_ws, size_t ws_size,
                              hipStream_t stream) {
    const float* x    = (const float*)d_in[0];
    const int*   ei   = (const int*)d_in[1];
    const int*   batch= (const int*)d_in[2];
    const float* W1   = (const float*)d_in[4];
    const float* as1  = (const float*)d_in[5];
    const float* ad1  = (const float*)d_in[6];
    const float* b1   = (const float*)d_in[7];
    const float* W2   = (const float*)d_in[8];
    const float* as2w = (const float*)d_in[9];
    const float* ad2w = (const float*)d_in[10];
    const float* b2v  = (const float*)d_in[11];
    const float* lw   = (const float*)d_in[12];
    const float* lb   = (const float*)d_in[13];
    float* out = (float*)d_out;

    const int N = in_sizes[0];            // 100000
    const int E = in_sizes[1] / 2;        // 3200000
    const int G = out_size / 10;          // 512
    const int* srcI = ei;
    const int* dstI = ei + E;
    const int NB = (N + 255) >> 8;        // 391 buckets of 256 nodes

    // workspace layout
    int*   gcur = (int*)d_ws;                                // 512
    unsigned int* packed = (unsigned int*)(gcur + 512);      // NB*BCAP (csr aliases)
    int*   rowS = (int*)(packed + (size_t)NB * BCAP);        // N
    int*   rowE = rowS + N;                                  // N
    float* h2   = (float*)(rowE + N);                        // 8N
    float* as2  = h2 + (size_t)8 * N;                        // N
    float* ad2  = as2 + N;                                   // N
    float* out2 = ad2 + N;                                   // 8N
    int*   gstart = (int*)(out2 + (size_t)8 * N);            // G+1

    const int B = 256;
    hipMemsetAsync(gcur, 0, 512 * sizeof(int), stream);

    kP_bucket<<<(E + TILE - 1) / TILE, 1024, 0, stream>>>(srcI, dstI, gcur, packed, E, NB);
    kL1<<<NB, 512, 0, stream>>>(gcur, packed, x, W1, as1, ad1, b1, W2, as2w, ad2w,
                                batch, gstart, rowS, rowE, h2, as2, ad2, N, G);
    kG2_gather<<<(N * 8 + B - 1) / B, B, 0, stream>>>(rowS, rowE, packed, as2, ad2, h2,
                                                      out2, N);
    kPool<<<(G * 64 + B - 1) / B, B, 0, stream>>>(out2, gstart, b2v, lw, lb, out, G);
}